// Round 3
// baseline (32.958 us; speedup 1.0000x reference)
//
#include <hip/hip_runtime.h>
#include <hip/hip_bf16.h>

// out[b,h,i,j] = mask[b,h,i,j] - bias[h, i-j+1023]
// bias depends only on the diagonal d = i-j+1023 -> 2047x8 table (64 KiB),
// then a pure streaming subtract (134 MB HBM traffic, memory-bound).

#define L_SEQ 1024
#define NDIAG (2 * L_SEQ - 1)   // 2047
#define NH 8
#define DIM 64

// clang native vector type: required by __builtin_nontemporal_load/store
typedef float f32x4 __attribute__((ext_vector_type(4)));

__device__ __forceinline__ float silu_f(float x) {
    return x / (1.0f + __expf(-x));
}

// 4 diagonals per 256-thread block; 64 lanes per diagonal.
__global__ __launch_bounds__(256) void build_bias_table(
    const float* __restrict__ W0, const float* __restrict__ b0,
    const float* __restrict__ W1, const float* __restrict__ b1,
    const float* __restrict__ W2, const float* __restrict__ b2,
    const float* __restrict__ Wf, const float* __restrict__ bf,
    float* __restrict__ tab /* [NH][NDIAG] */) {
    const int g = threadIdx.x >> 6;      // diag group 0..3
    const int t = threadIdx.x & 63;      // 0..63
    const int d = blockIdx.x * 4 + g;    // 0..2047 (guard 2047)
    const float rel = (float)(d - (L_SEQ - 1));

    __shared__ float sh[4][DIM];

    // layer 0: (1 -> 64)
    float h = silu_f(rel * W0[t] + b0[t]);
    sh[g][t] = h;
    __syncthreads();

    // layer 1: (64 -> 64)
    float acc = b1[t];
    #pragma unroll
    for (int k = 0; k < DIM; ++k) acc += sh[g][k] * W1[k * DIM + t];
    float h1 = silu_f(acc);
    __syncthreads();
    sh[g][t] = h1;
    __syncthreads();

    // layer 2: (64 -> 64)
    acc = b2[t];
    #pragma unroll
    for (int k = 0; k < DIM; ++k) acc += sh[g][k] * W2[k * DIM + t];
    float h2 = silu_f(acc);
    __syncthreads();
    sh[g][t] = h2;
    __syncthreads();

    // final: (64 -> 8)
    if (t < NH && d < NDIAG) {
        float a = bf[t];
        #pragma unroll
        for (int k = 0; k < DIM; ++k) a += sh[g][k] * Wf[k * NH + t];
        tab[t * NDIAG + d] = a;
    }
}

// Exact mapping: each thread handles float4 at idx and idx + half4.
// 32 B/lane, nontemporal streaming (no reuse of mask/out).
__global__ __launch_bounds__(256) void apply_bias(
    const f32x4* __restrict__ mask, const float* __restrict__ tab,
    f32x4* __restrict__ out, int half4) {
    const int idx = blockIdx.x * 256 + threadIdx.x;

    #pragma unroll
    for (int p = 0; p < 2; ++p) {
        const int id = idx + p * half4;
        const int n = id << 2;                  // flat element index
        const int j = n & (L_SEQ - 1);
        const int i = (n >> 10) & (L_SEQ - 1);
        const int h = (n >> 20) & (NH - 1);
        const float* tb = tab + h * NDIAG + (i - j + (L_SEQ - 1));
        const f32x4 m = __builtin_nontemporal_load(&mask[id]);
        f32x4 o;
        o.x = m.x - tb[0];
        o.y = m.y - tb[-1];
        o.z = m.z - tb[-2];
        o.w = m.w - tb[-3];
        __builtin_nontemporal_store(o, &out[id]);
    }
}

extern "C" void kernel_launch(void* const* d_in, const int* in_sizes, int n_in,
                              void* d_out, int out_size, void* d_ws, size_t ws_size,
                              hipStream_t stream) {
    const float* mask = (const float*)d_in[0];
    const float* W0 = (const float*)d_in[4];
    const float* b0 = (const float*)d_in[5];
    const float* W1 = (const float*)d_in[6];
    const float* b1 = (const float*)d_in[7];
    const float* W2 = (const float*)d_in[8];
    const float* b2 = (const float*)d_in[9];
    const float* Wf = (const float*)d_in[10];
    const float* bf = (const float*)d_in[11];
    float* out = (float*)d_out;

    float* tab = (float*)d_ws;   // NH * NDIAG floats = 64 KiB

    build_bias_table<<<(NDIAG + 3) / 4, 256, 0, stream>>>(
        W0, b0, W1, b1, W2, b2, Wf, bf, tab);

    const int n4 = out_size / 4;     // 4,194,304 float4
    const int half4 = n4 / 2;        // 2,097,152
    const int grid = half4 / 256;    // 8192 blocks, exact
    apply_bias<<<grid, 256, 0, stream>>>(
        (const f32x4*)mask, tab, (f32x4*)out, half4);
}

// Round 4
// 31.259 us; speedup vs baseline: 1.0544x; 1.0544x over previous
//
#include <hip/hip_runtime.h>
#include <hip/hip_bf16.h>

// out[b,h,i,j] = mask[b,h,i,j] - bias[h, i-j]
// bias depends only on d = i-j+1023 -> 8 x 2047 table (64 KiB).
// Stored REVERSED: rtab[h][d'] with d' = 1023 - i + j, so that for a fixed
// row (h,i) the j-sweep reads a contiguous ASCENDING window -> coalesced.

#define L_SEQ 1024
#define NDIAG (2 * L_SEQ - 1)   // 2047
#define NH 8
#define DIM 64

typedef float f32x4 __attribute__((ext_vector_type(4)));

__device__ __forceinline__ float silu_f(float x) {
    return x / (1.0f + __expf(-x));
}

// 4 diagonals per 256-thread block; 64 lanes per diagonal.
__global__ __launch_bounds__(256) void build_bias_table(
    const float* __restrict__ W0, const float* __restrict__ b0,
    const float* __restrict__ W1, const float* __restrict__ b1,
    const float* __restrict__ W2, const float* __restrict__ b2,
    const float* __restrict__ Wf, const float* __restrict__ bf,
    float* __restrict__ rtab /* [NH][NDIAG], reversed */) {
    const int g = threadIdx.x >> 6;      // diag group 0..3
    const int t = threadIdx.x & 63;      // 0..63
    const int d = blockIdx.x * 4 + g;    // 0..2047 (guard 2047)
    const float rel = (float)(d - (L_SEQ - 1));

    __shared__ float sh[4][DIM];

    // layer 0: (1 -> 64)
    float h = silu_f(rel * W0[t] + b0[t]);
    sh[g][t] = h;
    __syncthreads();

    // layer 1: (64 -> 64)
    float acc = b1[t];
    #pragma unroll
    for (int k = 0; k < DIM; ++k) acc += sh[g][k] * W1[k * DIM + t];
    float h1 = silu_f(acc);
    __syncthreads();
    sh[g][t] = h1;
    __syncthreads();

    // layer 2: (64 -> 64)
    acc = b2[t];
    #pragma unroll
    for (int k = 0; k < DIM; ++k) acc += sh[g][k] * W2[k * DIM + t];
    float h2 = silu_f(acc);
    __syncthreads();
    sh[g][t] = h2;
    __syncthreads();

    // final: (64 -> 8); write reversed: d' = NDIAG-1-d
    if (t < NH && d < NDIAG) {
        float a = bf[t];
        #pragma unroll
        for (int k = 0; k < DIM; ++k) a += sh[g][k] * Wf[k * NH + t];
        rtab[t * NDIAG + (NDIAG - 1 - d)] = a;
    }
}

// One block per output row (b,h,i). Thread t handles j = 4t..4t+3.
// rt[j] = rtab[h][1023 - i + j] = bias[h,i,j]: ascending contiguous reads.
__global__ __launch_bounds__(256) void apply_bias(
    const f32x4* __restrict__ mask, const float* __restrict__ rtab,
    f32x4* __restrict__ out) {
    const int row = blockIdx.x;               // 0 .. B*NH*L-1
    const int i = row & (L_SEQ - 1);
    const int h = (row >> 10) & (NH - 1);
    const float* rt = rtab + h * NDIAG + (L_SEQ - 1 - i);

    const int t = threadIdx.x;
    const int idx = row * 256 + t;
    const int j0 = t << 2;

    const f32x4 m = mask[idx];
    f32x4 o;
    o.x = m.x - rt[j0 + 0];
    o.y = m.y - rt[j0 + 1];
    o.z = m.z - rt[j0 + 2];
    o.w = m.w - rt[j0 + 3];
    out[idx] = o;
}

extern "C" void kernel_launch(void* const* d_in, const int* in_sizes, int n_in,
                              void* d_out, int out_size, void* d_ws, size_t ws_size,
                              hipStream_t stream) {
    const float* mask = (const float*)d_in[0];
    const float* W0 = (const float*)d_in[4];
    const float* b0 = (const float*)d_in[5];
    const float* W1 = (const float*)d_in[6];
    const float* b1 = (const float*)d_in[7];
    const float* W2 = (const float*)d_in[8];
    const float* b2 = (const float*)d_in[9];
    const float* Wf = (const float*)d_in[10];
    const float* bf = (const float*)d_in[11];
    float* out = (float*)d_out;

    float* rtab = (float*)d_ws;   // NH * NDIAG floats = 64 KiB

    build_bias_table<<<(NDIAG + 3) / 4, 256, 0, stream>>>(
        W0, b0, W1, b1, W2, b2, Wf, bf, rtab);

    const int rows = out_size / L_SEQ;   // B*NH*L = 16384
    apply_bias<<<rows, 256, 0, stream>>>(
        (const f32x4*)mask, rtab, (f32x4*)out);
}